// Round 1
// baseline (451.556 us; speedup 1.0000x reference)
//
#include <hip/hip_runtime.h>
#include <hip/hip_bf16.h>
#include <stdint.h>

typedef unsigned short u16;
typedef unsigned int u32;
typedef __attribute__((ext_vector_type(8))) short bf16x8;   // 8 bf16 in 4 VGPRs
typedef __attribute__((ext_vector_type(4))) float f32x4;

#define S_LEN 2048
#define D_DIM 1024
#define H_DIM 1024
#define BATCH 8
#define M_TOTAL (BATCH * S_LEN)   // 16384

__device__ __forceinline__ u16 f2b(float f) {
  u32 u = __builtin_bit_cast(u32, f);
  u32 r = (u + 0x7fffu + ((u >> 16) & 1u)) >> 16;   // RNE
  return (u16)r;
}
__device__ __forceinline__ float b2f(u16 v) {
  u32 u = ((u32)v) << 16;
  return __builtin_bit_cast(float, u);
}

// ---------------- cast x (fp32 -> bf16), 8 elems/thread ----------------
__global__ __launch_bounds__(256) void cast_x_kernel(const float* __restrict__ in,
                                                     u16* __restrict__ out, int n8) {
  int i = blockIdx.x * 256 + threadIdx.x;
  if (i >= n8) return;
  const float4* p = (const float4*)in;
  float4 a = p[2 * i], b = p[2 * i + 1];
  u32 w0 = (u32)f2b(a.x) | ((u32)f2b(a.y) << 16);
  u32 w1 = (u32)f2b(a.z) | ((u32)f2b(a.w) << 16);
  u32 w2 = (u32)f2b(b.x) | ((u32)f2b(b.y) << 16);
  u32 w3 = (u32)f2b(b.z) | ((u32)f2b(b.w) << 16);
  ((uint4*)out)[i] = make_uint4(w0, w1, w2, w3);
}

// ------------- transpose-cast W [d][h] fp32 -> Wt [h][d] bf16 -------------
__global__ __launch_bounds__(256) void wcast_kernel(const float* __restrict__ W,
                                                    u16* __restrict__ Wt) {
  __shared__ float tile[32][33];
  int h0 = blockIdx.x * 32, d0 = blockIdx.y * 32;
  int tx = threadIdx.x & 31, ty = threadIdx.x >> 5;
#pragma unroll
  for (int r = ty; r < 32; r += 8)
    tile[r][tx] = W[(size_t)(d0 + r) * H_DIM + h0 + tx];
  __syncthreads();
#pragma unroll
  for (int r = ty; r < 32; r += 8)
    Wt[(size_t)(h0 + r) * D_DIM + d0 + tx] = f2b(tile[tx][r]);
}

// ---------------- GEMM: C[M][N] = A[M][K] * Bt[N][K]^T (+bias) ----------------
// 128x128 block tile, 4 waves (2x2 of 64x64), BK=64, mfma_f32_16x16x32_bf16.
// Staging via global_load_lds width=16 with XOR chunk swizzle (swizzle applied to
// the GLOBAL source chunk so the LDS dest stays wave-uniform-base + lane*16).
// BIAS_MODE: 0 none, 1 bias[col], 2 bias[row]. OUT_BF16: store bf16 else fp32.
template <int BIAS_MODE, bool OUT_BF16>
__global__ __launch_bounds__(256) void gemm_bt(const u16* __restrict__ A,
                                               const u16* __restrict__ Bt,
                                               void* __restrict__ Cout,
                                               const float* __restrict__ bias,
                                               int M, int N, int K,
                                               long long aBatch, long long bBatch,
                                               long long cBatch) {
  __shared__ __align__(16) u16 As[128 * 64];
  __shared__ __align__(16) u16 Bs[128 * 64];
  const int tid = threadIdx.x;
  const int wave = tid >> 6, lane = tid & 63;
  const int quad = lane >> 4, lr = lane & 15;
  const int wr = (wave >> 1) * 64, wc = (wave & 1) * 64;
  const int row0 = blockIdx.x * 128, col0 = blockIdx.y * 128;
  A += (size_t)blockIdx.z * (size_t)aBatch;
  Bt += (size_t)blockIdx.z * (size_t)bBatch;

  f32x4 acc[4][4] = {};

  auto AsL = (__attribute__((address_space(3))) char*)As;
  auto BsL = (__attribute__((address_space(3))) char*)Bs;
  const char* Ab = (const char*)A;
  const char* Bb = (const char*)Bt;

  for (int k0 = 0; k0 < K; k0 += 64) {
    // ---- stage A and B tiles: 128 rows x 64 bf16 = 16 KB each, 4 rounds of 256x16B
#pragma unroll
    for (int rr = 0; rr < 4; ++rr) {
      int chunk = rr * 256 + tid;          // 0..1023, = row*8 + cc_store
      int row = chunk >> 3;
      int cs = (chunk & 7) ^ (row & 7);    // swizzled source chunk within the row
      const void* ga = Ab + (((size_t)(row0 + row) * K + (size_t)k0 + cs * 8) * 2);
      __builtin_amdgcn_global_load_lds(
          (const __attribute__((address_space(1))) void*)ga,
          (__attribute__((address_space(3))) void*)(AsL + chunk * 16), 16, 0, 0);
      const void* gb = Bb + (((size_t)(col0 + row) * K + (size_t)k0 + cs * 8) * 2);
      __builtin_amdgcn_global_load_lds(
          (const __attribute__((address_space(1))) void*)gb,
          (__attribute__((address_space(3))) void*)(BsL + chunk * 16), 16, 0, 0);
    }
    __syncthreads();
    // ---- compute: 2 k-steps of 32, 16 MFMAs each
#pragma unroll
    for (int ks = 0; ks < 2; ++ks) {
      bf16x8 af[4], bf[4];
#pragma unroll
      for (int i = 0; i < 4; ++i) {
        int r = wr + i * 16 + lr;
        int cc = (ks * 4 + quad) ^ (r & 7);
        af[i] = *(const bf16x8*)&As[r * 64 + cc * 8];
      }
#pragma unroll
      for (int j = 0; j < 4; ++j) {
        int r = wc + j * 16 + lr;
        int cc = (ks * 4 + quad) ^ (r & 7);
        bf[j] = *(const bf16x8*)&Bs[r * 64 + cc * 8];
      }
#pragma unroll
      for (int i = 0; i < 4; ++i)
#pragma unroll
        for (int j = 0; j < 4; ++j)
          acc[i][j] = __builtin_amdgcn_mfma_f32_16x16x32_bf16(af[i], bf[j],
                                                              acc[i][j], 0, 0, 0);
    }
    __syncthreads();
  }

  // ---- epilogue: C/D layout col=lane&15, row=quad*4+reg
  if constexpr (OUT_BF16) {
    u16* C = (u16*)Cout + (size_t)blockIdx.z * (size_t)cBatch;
#pragma unroll
    for (int i = 0; i < 4; ++i) {
#pragma unroll
      for (int j = 0; j < 4; ++j) {
        int c = col0 + wc + j * 16 + lr;
        float bcol = (BIAS_MODE == 1) ? bias[c] : 0.f;
#pragma unroll
        for (int ii = 0; ii < 4; ++ii) {
          int r = row0 + wr + i * 16 + quad * 4 + ii;
          float v = acc[i][j][ii] + bcol;
          if (BIAS_MODE == 2) v += bias[r];
          C[(size_t)r * N + c] = f2b(v);
        }
      }
    }
  } else {
    float* C = (float*)Cout + (size_t)blockIdx.z * (size_t)cBatch;
#pragma unroll
    for (int i = 0; i < 4; ++i) {
#pragma unroll
      for (int j = 0; j < 4; ++j) {
        int c = col0 + wc + j * 16 + lr;
        float bcol = (BIAS_MODE == 1) ? bias[c] : 0.f;
#pragma unroll
        for (int ii = 0; ii < 4; ++ii) {
          int r = row0 + wr + i * 16 + quad * 4 + ii;
          float v = acc[i][j][ii] + bcol;
          if (BIAS_MODE == 2) v += bias[r];
          C[(size_t)r * N + c] = v;
        }
      }
    }
  }
}

// ---------------- row softmax over 2048 bf16, in place, scale folded ----------------
__global__ __launch_bounds__(256) void softmax_kernel(u16* __restrict__ S, float scale) {
  __shared__ float red[8];
  const int row = blockIdx.x;
  const int tid = threadIdx.x;
  const int wave = tid >> 6, lane = tid & 63;
  u16* rp = S + (size_t)row * S_LEN;
  uint4 q = ((const uint4*)rp)[tid];
  u32 w[4] = {q.x, q.y, q.z, q.w};
  float v[8];
#pragma unroll
  for (int k = 0; k < 4; ++k) {
    v[2 * k] = b2f((u16)(w[k] & 0xffffu)) * scale;
    v[2 * k + 1] = b2f((u16)(w[k] >> 16)) * scale;
  }
  float m = v[0];
#pragma unroll
  for (int k = 1; k < 8; ++k) m = fmaxf(m, v[k]);
#pragma unroll
  for (int off = 32; off > 0; off >>= 1) m = fmaxf(m, __shfl_xor(m, off));
  if (lane == 0) red[wave] = m;
  __syncthreads();
  m = fmaxf(fmaxf(red[0], red[1]), fmaxf(red[2], red[3]));
  float e[8], s = 0.f;
#pragma unroll
  for (int k = 0; k < 8; ++k) {
    e[k] = __expf(v[k] - m);
    s += e[k];
  }
#pragma unroll
  for (int off = 32; off > 0; off >>= 1) s += __shfl_xor(s, off);
  if (lane == 0) red[4 + wave] = s;
  __syncthreads();
  float inv = 1.0f / (red[4] + red[5] + red[6] + red[7]);
  u32 o[4];
#pragma unroll
  for (int k = 0; k < 4; ++k)
    o[k] = (u32)f2b(e[2 * k] * inv) | ((u32)f2b(e[2 * k + 1] * inv) << 16);
  ((uint4*)rp)[tid] = make_uint4(o[0], o[1], o[2], o[3]);
}

extern "C" void kernel_launch(void* const* d_in, const int* in_sizes, int n_in,
                              void* d_out, int out_size, void* d_ws, size_t ws_size,
                              hipStream_t stream) {
  const float* x = (const float*)d_in[0];
  const float* Wq = (const float*)d_in[1];
  const float* bq = (const float*)d_in[2];
  const float* Wk = (const float*)d_in[3];
  const float* bk = (const float*)d_in[4];
  const float* Wv = (const float*)d_in[5];
  const float* bv = (const float*)d_in[6];
  float* out = (float*)d_out;

  // workspace layout (bytes): total ~198 MB
  char* ws = (char*)d_ws;
  u16* xb = (u16*)ws;  ws += (size_t)M_TOTAL * D_DIM * 2;          // 33.5 MB
  u16* Wtq = (u16*)ws; ws += (size_t)H_DIM * D_DIM * 2;            // 2 MB
  u16* Wtk = (u16*)ws; ws += (size_t)H_DIM * D_DIM * 2;
  u16* Wtv = (u16*)ws; ws += (size_t)H_DIM * D_DIM * 2;
  u16* Qm = (u16*)ws;  ws += (size_t)M_TOTAL * H_DIM * 2;          // 33.5 MB
  u16* Km = (u16*)ws;  ws += (size_t)M_TOTAL * H_DIM * 2;          // 33.5 MB
  u16* Vt = (u16*)ws;  ws += (size_t)BATCH * H_DIM * S_LEN * 2;    // 33.5 MB  [b][h][s]
  u16* Sm = (u16*)ws;  ws += (size_t)BATCH * S_LEN * S_LEN * 2;    // 67 MB    [b][q][k]

  // 1) casts
  cast_x_kernel<<<(M_TOTAL * D_DIM / 8 + 255) / 256, 256, 0, stream>>>(
      x, xb, M_TOTAL * D_DIM / 8);
  wcast_kernel<<<dim3(32, 32), 256, 0, stream>>>(Wq, Wtq);
  wcast_kernel<<<dim3(32, 32), 256, 0, stream>>>(Wk, Wtk);
  wcast_kernel<<<dim3(32, 32), 256, 0, stream>>>(Wv, Wtv);

  // 2) Q = xb * Wtq^T + bq ; K likewise  (M=16384, N=1024, K=1024)
  gemm_bt<1, true><<<dim3(128, 8, 1), 256, 0, stream>>>(
      xb, Wtq, Qm, bq, M_TOTAL, H_DIM, D_DIM, 0, 0, 0);
  gemm_bt<1, true><<<dim3(128, 8, 1), 256, 0, stream>>>(
      xb, Wtk, Km, bk, M_TOTAL, H_DIM, D_DIM, 0, 0, 0);

  // 3) Vt[b][h][s] = Wtv * xb_b^T + bv[row]  (M=1024, N=2048, K=1024, batched)
  gemm_bt<2, true><<<dim3(8, 16, BATCH), 256, 0, stream>>>(
      Wtv, xb, Vt, bv, H_DIM, S_LEN, D_DIM,
      0LL, (long long)S_LEN * D_DIM, (long long)H_DIM * S_LEN);

  // 4) raw scores S[b][q][k] = Q_b * K_b^T  (M=N=2048, K=1024, batched)
  gemm_bt<0, true><<<dim3(16, 16, BATCH), 256, 0, stream>>>(
      Qm, Km, Sm, nullptr, S_LEN, S_LEN, H_DIM,
      (long long)S_LEN * H_DIM, (long long)S_LEN * H_DIM, (long long)S_LEN * S_LEN);

  // 5) softmax rows (scale = 1/sqrt(1024) = 1/32 folded in)
  softmax_kernel<<<M_TOTAL, 256, 0, stream>>>(Sm, 0.03125f);

  // 6) out[b][q][h] = P_b * Vt_b^T  (M=2048, N=1024, K=2048, fp32 out)
  gemm_bt<0, false><<<dim3(16, 8, BATCH), 256, 0, stream>>>(
      Sm, Vt, out, nullptr, S_LEN, H_DIM, S_LEN,
      (long long)S_LEN * S_LEN, (long long)H_DIM * S_LEN, (long long)S_LEN * H_DIM);
}